// Round 1
// baseline (634.929 us; speedup 1.0000x reference)
//
#include <hip/hip_runtime.h>

#define DF 128

// ---------------- CSR build ----------------

__global__ void k_hist(const int* __restrict__ dst, int* __restrict__ cnt, int e){
  int i = blockIdx.x*256 + threadIdx.x;
  if(i<e) atomicAdd(&cnt[dst[i]], 1);
}

__global__ void k_scan1(const int* __restrict__ cnt, int* __restrict__ ex,
                        int* __restrict__ bsum, int n){
  __shared__ int sh[256];
  int t = threadIdx.x;
  int base = blockIdx.x*1024 + t*4;
  int c0 = (base  <n)?cnt[base  ]:0;
  int c1 = (base+1<n)?cnt[base+1]:0;
  int c2 = (base+2<n)?cnt[base+2]:0;
  int c3 = (base+3<n)?cnt[base+3]:0;
  int s = c0+c1+c2+c3;
  sh[t]=s; __syncthreads();
  for(int off=1; off<256; off<<=1){
    int v = (t>=off)? sh[t-off]:0;
    __syncthreads();
    sh[t]+=v;
    __syncthreads();
  }
  int excl = sh[t]-s;
  if(t==255) bsum[blockIdx.x]=sh[255];
  if(base  <n) ex[base  ]=excl;
  if(base+1<n) ex[base+1]=excl+c0;
  if(base+2<n) ex[base+2]=excl+c0+c1;
  if(base+3<n) ex[base+3]=excl+c0+c1+c2;
}

__global__ void k_scan2(int* bsum, int nb){
  if(threadIdx.x==0 && blockIdx.x==0){
    int acc=0;
    for(int i=0;i<nb;i++){ int v=bsum[i]; bsum[i]=acc; acc+=v; }
  }
}

__global__ void k_scan3(const int* __restrict__ cnt, int* __restrict__ rp,
                        int* __restrict__ cur, float* __restrict__ dinv,
                        const int* __restrict__ bsum, int n, int e){
  int i = blockIdx.x*256 + threadIdx.x;
  if(i<n){
    int v = rp[i] + bsum[i>>10];
    rp[i]=v; cur[i]=v;
    dinv[i] = rsqrtf((float)(cnt[i]+1));
  } else if(i==n){
    rp[n]=e;
  }
}

__global__ void k_scatter(const int* __restrict__ src, const int* __restrict__ dst,
                          int* __restrict__ cur, int* __restrict__ csr, int e){
  int i = blockIdx.x*256+threadIdx.x;
  if(i<e){
    int d = dst[i];
    int p = atomicAdd(&cur[d],1);
    csr[p] = src[i];
  }
}

// ---------------- GEMM: ht = dinv .* (X @ W), D=128 -> 128 ----------------
// 64x64 tile per block (blockIdx.y selects col half), 256 threads, 4x4 per thread.
// LDS: xs 64x132 + wt 64x132 = 67.6KB -> 2 blocks/CU.

__launch_bounds__(256)
__global__ void k_gemm128(const float* __restrict__ X, const float* __restrict__ W,
                          const float* __restrict__ dinv, float* __restrict__ out, int n){
  __shared__ float xs[64][132];
  __shared__ float wt[64][132];
  int row0 = blockIdx.x*64;
  int c0g  = blockIdx.y*64;
  int t = threadIdx.x;
  // stage W^T half: wt[c][k] = W[k][c0g+c]
  for(int idx=t; idx<64*128; idx+=256){
    int k = idx>>6, c = idx&63;
    wt[c][k] = W[k*DF + c0g + c];
  }
  // stage X tile
  for(int idx=t; idx<64*32; idx+=256){
    int r = idx>>5, k4=(idx&31)*4;
    int gr = row0+r;
    float4 v = (gr<n)? *(const float4*)(X + (size_t)gr*DF + k4)
                     : make_float4(0.f,0.f,0.f,0.f);
    xs[r][k4]=v.x; xs[r][k4+1]=v.y; xs[r][k4+2]=v.z; xs[r][k4+3]=v.w;
  }
  __syncthreads();
  int tr=t>>4, tc=t&15;
  int r0=tr*4;
  float acc[4][4]={};
  for(int k=0;k<128;k+=4){
    float4 a0=*(const float4*)&xs[r0  ][k];
    float4 a1=*(const float4*)&xs[r0+1][k];
    float4 a2=*(const float4*)&xs[r0+2][k];
    float4 a3=*(const float4*)&xs[r0+3][k];
    float4 b0=*(const float4*)&wt[tc   ][k];
    float4 b1=*(const float4*)&wt[tc+16][k];
    float4 b2=*(const float4*)&wt[tc+32][k];
    float4 b3=*(const float4*)&wt[tc+48][k];
#define DOT(ACC,A,B) ACC = fmaf(A.x,B.x, fmaf(A.y,B.y, fmaf(A.z,B.z, fmaf(A.w,B.w, ACC))))
    DOT(acc[0][0],a0,b0); DOT(acc[0][1],a0,b1); DOT(acc[0][2],a0,b2); DOT(acc[0][3],a0,b3);
    DOT(acc[1][0],a1,b0); DOT(acc[1][1],a1,b1); DOT(acc[1][2],a1,b2); DOT(acc[1][3],a1,b3);
    DOT(acc[2][0],a2,b0); DOT(acc[2][1],a2,b1); DOT(acc[2][2],a2,b2); DOT(acc[2][3],a2,b3);
    DOT(acc[3][0],a3,b0); DOT(acc[3][1],a3,b1); DOT(acc[3][2],a3,b2); DOT(acc[3][3],a3,b3);
#undef DOT
  }
  for(int i=0;i<4;i++){
    int gr=row0+r0+i;
    if(gr<n){
      float dv=dinv[gr];
      size_t ob = (size_t)gr*DF + c0g + tc;
      out[ob     ] = dv*acc[i][0];
      out[ob + 16] = dv*acc[i][1];
      out[ob + 32] = dv*acc[i][2];
      out[ob + 48] = dv*acc[i][3];
    }
  }
}

// ---------------- Aggregate: out[i] = act(dinv[i]*(ht[i] + sum ht[src]) + b) ----------------
// 32 lanes (float4 each) per node, 8 nodes per 256-block.

__launch_bounds__(256)
__global__ void k_agg128(const float* __restrict__ ht, const int* __restrict__ rp,
                         const int* __restrict__ cs, const float* __restrict__ dinv,
                         const float* __restrict__ bias, float* __restrict__ out,
                         int n, int relu){
  int t=threadIdx.x;
  int node = blockIdx.x*8 + (t>>5);
  if(node>=n) return;
  int c4 = (t&31)*4;
  float4 acc = *(const float4*)(ht + (size_t)node*DF + c4);  // self-loop term
  float4 acc2 = make_float4(0.f,0.f,0.f,0.f);
  int e0=rp[node], e1=rp[node+1];
  int e=e0;
  for(; e+1<e1; e+=2){
    int s0=cs[e], s1=cs[e+1];
    float4 v0 = *(const float4*)(ht + (size_t)s0*DF + c4);
    float4 v1 = *(const float4*)(ht + (size_t)s1*DF + c4);
    acc.x+=v0.x;  acc.y+=v0.y;  acc.z+=v0.z;  acc.w+=v0.w;
    acc2.x+=v1.x; acc2.y+=v1.y; acc2.z+=v1.z; acc2.w+=v1.w;
  }
  if(e<e1){
    int s0=cs[e];
    float4 v0=*(const float4*)(ht + (size_t)s0*DF + c4);
    acc.x+=v0.x; acc.y+=v0.y; acc.z+=v0.z; acc.w+=v0.w;
  }
  acc.x+=acc2.x; acc.y+=acc2.y; acc.z+=acc2.z; acc.w+=acc2.w;
  float dv=dinv[node];
  const float4 bz = *(const float4*)(bias + c4);
  float4 o;
  o.x = fmaf(dv, acc.x, bz.x);
  o.y = fmaf(dv, acc.y, bz.y);
  o.z = fmaf(dv, acc.z, bz.z);
  o.w = fmaf(dv, acc.w, bz.w);
  if(relu){
    o.x=fmaxf(o.x,0.f); o.y=fmaxf(o.y,0.f); o.z=fmaxf(o.z,0.f); o.w=fmaxf(o.w,0.f);
  }
  *(float4*)(out + (size_t)node*DF + c4) = o;
}

// ---------------- Final layer: 128 -> 5 ----------------

__launch_bounds__(256)
__global__ void k_gemm5(const float* __restrict__ X, const float* __restrict__ W2,
                        const float* __restrict__ dinv, float* __restrict__ out, int n){
  __shared__ float xs[32][129];
  __shared__ float wsh[640];
  int t=threadIdx.x;
  int row0=blockIdx.x*32;
  for(int idx=t; idx<640; idx+=256) wsh[idx]=W2[idx];
  for(int idx=t; idx<1024; idx+=256){
    int r=idx>>5, k4=(idx&31)*4;
    int gr=row0+r;
    float4 v = (gr<n)? *(const float4*)(X+(size_t)gr*DF+k4) : make_float4(0.f,0.f,0.f,0.f);
    xs[r][k4]=v.x; xs[r][k4+1]=v.y; xs[r][k4+2]=v.z; xs[r][k4+3]=v.w;
  }
  __syncthreads();
  int r=t>>3, c=t&7;
  int gr=row0+r;
  if(c<5 && gr<n){
    float acc=0.f;
    #pragma unroll
    for(int k=0;k<128;k++) acc = fmaf(xs[r][k], wsh[k*5+c], acc);
    out[(size_t)gr*5+c] = dinv[gr]*acc;
  }
}

__global__ void k_agg5(const float* __restrict__ ht, const int* __restrict__ rp,
                       const int* __restrict__ cs, const float* __restrict__ dinv,
                       const float* __restrict__ b2, float* __restrict__ out, int n){
  int idx = blockIdx.x*256+threadIdx.x;
  int node = idx>>3, c = idx&7;
  if(node>=n || c>=5) return;
  float acc = ht[(size_t)node*5+c];
  int e0=rp[node], e1=rp[node+1];
  for(int e=e0;e<e1;e++){
    acc += ht[(size_t)cs[e]*5+c];
  }
  out[(size_t)node*5+c] = fmaf(dinv[node], acc, b2[c]);
}

// ---------------- launch ----------------

extern "C" void kernel_launch(void* const* d_in, const int* in_sizes, int n_in,
                              void* d_out, int out_size, void* d_ws, size_t ws_size,
                              hipStream_t stream){
  const float* x  = (const float*)d_in[0];
  const int*   ei = (const int*)  d_in[1];
  const float* W0 = (const float*)d_in[2];
  const float* b0 = (const float*)d_in[3];
  const float* W1 = (const float*)d_in[4];
  const float* b1 = (const float*)d_in[5];
  const float* W2 = (const float*)d_in[6];
  const float* b2 = (const float*)d_in[7];
  int n = in_sizes[0]/DF;
  int e = in_sizes[1]/2;
  const int* srcp = ei;
  const int* dstp = ei + e;

  char* ws = (char*)d_ws;
  size_t off=0;
  auto take=[&](size_t bytes)->char*{
    char* p = ws+off;
    off = (off+bytes+511)&~(size_t)511;
    return p;
  };
  int*   cnt  = (int*)  take((size_t)n*4);
  int*   bsum = (int*)  take(512);
  int*   rp   = (int*)  take((size_t)(n+1)*4);
  int*   cur  = (int*)  take((size_t)n*4);
  int*   csr  = (int*)  take((size_t)e*4);
  float* dinv = (float*)take((size_t)n*4);
  float* bufA = (float*)take((size_t)n*DF*4);
  float* bufB = (float*)take((size_t)n*DF*4);
  // layer-3 ht (n x 5) reuses bufA

  hipMemsetAsync(cnt, 0, (size_t)n*4, stream);
  hipMemsetAsync(bsum, 0, 512, stream);

  int nb = (n+1023)/1024;
  k_hist   <<<(e+255)/256, 256, 0, stream>>>(dstp, cnt, e);
  k_scan1  <<<nb,          256, 0, stream>>>(cnt, rp, bsum, n);
  k_scan2  <<<1,            64, 0, stream>>>(bsum, nb);
  k_scan3  <<<(n+1+255)/256,256,0, stream>>>(cnt, rp, cur, dinv, bsum, n, e);
  k_scatter<<<(e+255)/256, 256, 0, stream>>>(srcp, dstp, cur, csr, e);

  dim3 gg((n+63)/64, 2);
  k_gemm128<<<gg,          256, 0, stream>>>(x,    W0, dinv, bufA, n);
  k_agg128 <<<(n+7)/8,     256, 0, stream>>>(bufA, rp, csr, dinv, b0, bufB, n, 1);
  k_gemm128<<<gg,          256, 0, stream>>>(bufB, W1, dinv, bufA, n);
  k_agg128 <<<(n+7)/8,     256, 0, stream>>>(bufA, rp, csr, dinv, b1, bufB, n, 1);
  k_gemm5  <<<(n+31)/32,   256, 0, stream>>>(bufB, W2, dinv, bufA, n);
  k_agg5   <<<((n*8)+255)/256,256,0,stream>>>(bufA, rp, csr, dinv, b2, (float*)d_out, n);
}

// Round 5
// 484.138 us; speedup vs baseline: 1.3115x; 1.3115x over previous
//
#include <hip/hip_runtime.h>

#define DF 128
#define RB 512            // nodes per bucket (power of two)
#define RB_SHIFT 9
#define NB_MAX 256        // supports n <= 131072
#define CHUNK 8192        // edges per binning block

// ---------------- CSR build (bucketed, coalesced) ----------------

__global__ void k_bhist(const int* __restrict__ dst, int* __restrict__ bcnt, int e){
  __shared__ int h[NB_MAX];
  int t = threadIdx.x;
  h[t] = 0;
  __syncthreads();
  int base = blockIdx.x*CHUNK;
  for(int k=0;k<CHUNK/256;k++){
    int i = base + t + k*256;
    if(i<e) atomicAdd(&h[dst[i]>>RB_SHIFT], 1);
  }
  __syncthreads();
  if(h[t]) atomicAdd(&bcnt[t], h[t]);
}

__global__ void k_bscan(const int* __restrict__ bcnt, int* __restrict__ bbase,
                        int* __restrict__ bcur, int e){
  __shared__ int sh[NB_MAX];
  int t = threadIdx.x;
  int c = bcnt[t];
  sh[t] = c;
  __syncthreads();
  for(int off=1; off<256; off<<=1){
    int v = (t>=off)? sh[t-off]:0;
    __syncthreads();
    sh[t]+=v;
    __syncthreads();
  }
  int excl = sh[t]-c;
  bbase[t]=excl; bcur[t]=excl;
  if(t==255) bbase[256]=sh[255];   // == e
}

__launch_bounds__(256)
__global__ void k_binscatter(const int* __restrict__ src, const int* __restrict__ dst,
                             int* __restrict__ bcur, int2* __restrict__ binned, int e){
  __shared__ int h[NB_MAX];
  __shared__ int lexcl[NB_MAX];
  __shared__ int lcur[NB_MAX];
  __shared__ int gbase[NB_MAX];
  __shared__ int2 pairs[CHUNK];
  int t = threadIdx.x;
  int c0 = blockIdx.x*CHUNK;
  int cc = min(CHUNK, e - c0);
  h[t]=0;
  __syncthreads();
  for(int k=0;k<CHUNK/256;k++){
    int i = t + k*256;
    if(i<cc) atomicAdd(&h[dst[c0+i]>>RB_SHIFT], 1);
  }
  __syncthreads();
  int hc = h[t];
  lexcl[t]=hc;
  __syncthreads();
  for(int off=1; off<256; off<<=1){
    int v = (t>=off)? lexcl[t-off]:0;
    __syncthreads();
    lexcl[t]+=v;
    __syncthreads();
  }
  int incl = lexcl[t];          // own index only; no barrier needed
  lexcl[t] = incl - hc;
  lcur[t]  = incl - hc;
  gbase[t] = hc ? atomicAdd(&bcur[t], hc) : 0;
  __syncthreads();
  // phase 2: place pairs into LDS in bucket-sorted order
  for(int k=0;k<CHUNK/256;k++){
    int i = t + k*256;
    if(i<cc){
      int d = dst[c0+i], s = src[c0+i];
      int lp = atomicAdd(&lcur[d>>RB_SHIFT], 1);
      pairs[lp] = make_int2(d, s);
    }
  }
  __syncthreads();
  // phase 3: coalesced write-out of bucket-contiguous runs
  for(int k=0;k<CHUNK/256;k++){
    int p = t + k*256;
    if(p<cc){
      int2 pr = pairs[p];
      int b = pr.x>>RB_SHIFT;
      binned[gbase[b] + (p - lexcl[b])] = pr;
    }
  }
}

__launch_bounds__(256)
__global__ void k_localcsr(const int2* __restrict__ binned, const int* __restrict__ bbase,
                           int* __restrict__ rp, int* __restrict__ csr,
                           float* __restrict__ dinv, int n, int e){
  __shared__ int cnt[RB];
  __shared__ int sh[256];
  __shared__ int cur[RB];
  int b = blockIdx.x, t = threadIdx.x;
  int node0 = b<<RB_SHIFT;
  int e0 = bbase[b], e1 = bbase[b+1];
  cnt[t]=0; cnt[t+256]=0;
  __syncthreads();
  for(int i=e0+t; i<e1; i+=256)
    atomicAdd(&cnt[binned[i].x - node0], 1);
  __syncthreads();
  int c0 = cnt[2*t], c1 = cnt[2*t+1];
  int s = c0+c1;
  sh[t]=s;
  __syncthreads();
  for(int off=1; off<256; off<<=1){
    int v = (t>=off)? sh[t-off]:0;
    __syncthreads();
    sh[t]+=v;
    __syncthreads();
  }
  int excl = sh[t]-s;
  int g0 = node0+2*t, g1 = node0+2*t+1;
  if(g0<n){ rp[g0]=e0+excl;    dinv[g0]=rsqrtf((float)(c0+1)); }
  if(g1<n){ rp[g1]=e0+excl+c0; dinv[g1]=rsqrtf((float)(c1+1)); }
  cur[2*t]=excl; cur[2*t+1]=excl+c0;
  if(b==0 && t==0) rp[n]=e;
  __syncthreads();
  for(int i=e0+t; i<e1; i+=256){
    int2 pr = binned[i];
    int lp = atomicAdd(&cur[pr.x - node0], 1);
    csr[e0+lp] = pr.y;       // 32KB region, single block -> L2-local
  }
}

// ---------------- GEMM: ht = dinv .* (X @ W), D=128 -> 128 ----------------

__launch_bounds__(256)
__global__ void k_gemm128(const float* __restrict__ X, const float* __restrict__ W,
                          const float* __restrict__ dinv, float* __restrict__ out, int n){
  __shared__ float xs[64][132];
  __shared__ float wt[64][132];
  int row0 = blockIdx.x*64;
  int c0g  = blockIdx.y*64;
  int t = threadIdx.x;
  for(int idx=t; idx<64*128; idx+=256){
    int k = idx>>6, c = idx&63;
    wt[c][k] = W[k*DF + c0g + c];
  }
  for(int idx=t; idx<64*32; idx+=256){
    int r = idx>>5, k4=(idx&31)*4;
    int gr = row0+r;
    float4 v = (gr<n)? *(const float4*)(X + (size_t)gr*DF + k4)
                     : make_float4(0.f,0.f,0.f,0.f);
    xs[r][k4]=v.x; xs[r][k4+1]=v.y; xs[r][k4+2]=v.z; xs[r][k4+3]=v.w;
  }
  __syncthreads();
  int tr=t>>4, tc=t&15;
  int r0=tr*4;
  float acc[4][4]={};
  for(int k=0;k<128;k+=4){
    float4 a0=*(const float4*)&xs[r0  ][k];
    float4 a1=*(const float4*)&xs[r0+1][k];
    float4 a2=*(const float4*)&xs[r0+2][k];
    float4 a3=*(const float4*)&xs[r0+3][k];
    float4 b0=*(const float4*)&wt[tc   ][k];
    float4 b1=*(const float4*)&wt[tc+16][k];
    float4 b2=*(const float4*)&wt[tc+32][k];
    float4 b3=*(const float4*)&wt[tc+48][k];
#define DOT(ACC,A,B) ACC = fmaf(A.x,B.x, fmaf(A.y,B.y, fmaf(A.z,B.z, fmaf(A.w,B.w, ACC))))
    DOT(acc[0][0],a0,b0); DOT(acc[0][1],a0,b1); DOT(acc[0][2],a0,b2); DOT(acc[0][3],a0,b3);
    DOT(acc[1][0],a1,b0); DOT(acc[1][1],a1,b1); DOT(acc[1][2],a1,b2); DOT(acc[1][3],a1,b3);
    DOT(acc[2][0],a2,b0); DOT(acc[2][1],a2,b1); DOT(acc[2][2],a2,b2); DOT(acc[2][3],a2,b3);
    DOT(acc[3][0],a3,b0); DOT(acc[3][1],a3,b1); DOT(acc[3][2],a3,b2); DOT(acc[3][3],a3,b3);
#undef DOT
  }
  for(int i=0;i<4;i++){
    int gr=row0+r0+i;
    if(gr<n){
      float dv=dinv[gr];
      size_t ob = (size_t)gr*DF + c0g + tc;
      out[ob     ] = dv*acc[i][0];
      out[ob + 16] = dv*acc[i][1];
      out[ob + 32] = dv*acc[i][2];
      out[ob + 48] = dv*acc[i][3];
    }
  }
}

// ---------------- Aggregate ----------------

__launch_bounds__(256)
__global__ void k_agg128(const float* __restrict__ ht, const int* __restrict__ rp,
                         const int* __restrict__ cs, const float* __restrict__ dinv,
                         const float* __restrict__ bias, float* __restrict__ out,
                         int n, int relu){
  int t=threadIdx.x;
  int node = blockIdx.x*8 + (t>>5);
  if(node>=n) return;
  int c4 = (t&31)*4;
  float4 acc = *(const float4*)(ht + (size_t)node*DF + c4);  // self-loop
  float4 acc2 = make_float4(0.f,0.f,0.f,0.f);
  int e0=rp[node], e1=rp[node+1];
  int e=e0;
  for(; e+1<e1; e+=2){
    int s0=cs[e], s1=cs[e+1];
    float4 v0 = *(const float4*)(ht + (size_t)s0*DF + c4);
    float4 v1 = *(const float4*)(ht + (size_t)s1*DF + c4);
    acc.x+=v0.x;  acc.y+=v0.y;  acc.z+=v0.z;  acc.w+=v0.w;
    acc2.x+=v1.x; acc2.y+=v1.y; acc2.z+=v1.z; acc2.w+=v1.w;
  }
  if(e<e1){
    int s0=cs[e];
    float4 v0=*(const float4*)(ht + (size_t)s0*DF + c4);
    acc.x+=v0.x; acc.y+=v0.y; acc.z+=v0.z; acc.w+=v0.w;
  }
  acc.x+=acc2.x; acc.y+=acc2.y; acc.z+=acc2.z; acc.w+=acc2.w;
  float dv=dinv[node];
  const float4 bz = *(const float4*)(bias + c4);
  float4 o;
  o.x = fmaf(dv, acc.x, bz.x);
  o.y = fmaf(dv, acc.y, bz.y);
  o.z = fmaf(dv, acc.z, bz.z);
  o.w = fmaf(dv, acc.w, bz.w);
  if(relu){
    o.x=fmaxf(o.x,0.f); o.y=fmaxf(o.y,0.f); o.z=fmaxf(o.z,0.f); o.w=fmaxf(o.w,0.f);
  }
  *(float4*)(out + (size_t)node*DF + c4) = o;
}

// ---------------- Final layer: 128 -> 5 ----------------

__launch_bounds__(256)
__global__ void k_gemm5(const float* __restrict__ X, const float* __restrict__ W2,
                        const float* __restrict__ dinv, float* __restrict__ out, int n){
  __shared__ float xs[32][129];
  __shared__ float wsh[640];
  int t=threadIdx.x;
  int row0=blockIdx.x*32;
  for(int idx=t; idx<640; idx+=256) wsh[idx]=W2[idx];
  for(int idx=t; idx<1024; idx+=256){
    int r=idx>>5, k4=(idx&31)*4;
    int gr=row0+r;
    float4 v = (gr<n)? *(const float4*)(X+(size_t)gr*DF+k4) : make_float4(0.f,0.f,0.f,0.f);
    xs[r][k4]=v.x; xs[r][k4+1]=v.y; xs[r][k4+2]=v.z; xs[r][k4+3]=v.w;
  }
  __syncthreads();
  int r=t>>3, c=t&7;
  int gr=row0+r;
  if(c<5 && gr<n){
    float acc=0.f;
    #pragma unroll
    for(int k=0;k<128;k++) acc = fmaf(xs[r][k], wsh[k*5+c], acc);
    out[(size_t)gr*5+c] = dinv[gr]*acc;
  }
}

__global__ void k_agg5(const float* __restrict__ ht, const int* __restrict__ rp,
                       const int* __restrict__ cs, const float* __restrict__ dinv,
                       const float* __restrict__ b2, float* __restrict__ out, int n){
  int idx = blockIdx.x*256+threadIdx.x;
  int node = idx>>3, c = idx&7;
  if(node>=n || c>=5) return;
  float acc = ht[(size_t)node*5+c];
  int e0=rp[node], e1=rp[node+1];
  for(int e=e0;e<e1;e++){
    acc += ht[(size_t)cs[e]*5+c];
  }
  out[(size_t)node*5+c] = fmaf(dinv[node], acc, b2[c]);
}

// ---------------- launch ----------------

extern "C" void kernel_launch(void* const* d_in, const int* in_sizes, int n_in,
                              void* d_out, int out_size, void* d_ws, size_t ws_size,
                              hipStream_t stream){
  const float* x  = (const float*)d_in[0];
  const int*   ei = (const int*)  d_in[1];
  const float* W0 = (const float*)d_in[2];
  const float* b0 = (const float*)d_in[3];
  const float* W1 = (const float*)d_in[4];
  const float* b1 = (const float*)d_in[5];
  const float* W2 = (const float*)d_in[6];
  const float* b2 = (const float*)d_in[7];
  int n = in_sizes[0]/DF;
  int e = in_sizes[1]/2;
  const int* srcp = ei;
  const int* dstp = ei + e;

  char* ws = (char*)d_ws;
  size_t off=0;
  auto take=[&](size_t bytes)->char*{
    char* p = ws+off;
    off = (off+bytes+511)&~(size_t)511;
    return p;
  };
  int*   bcnt = (int*)  take((size_t)NB_MAX*4);
  int*   bbase= (int*)  take((size_t)(NB_MAX+1)*4);
  int*   bcur = (int*)  take((size_t)NB_MAX*4);
  int*   rp   = (int*)  take((size_t)(n+1)*4);
  int*   csr  = (int*)  take((size_t)e*4);
  float* dinv = (float*)take((size_t)n*4);
  float* bufA = (float*)take((size_t)n*DF*4);
  float* bufB = (float*)take((size_t)n*DF*4);
  int2*  binned = (int2*)bufB;   // dead before first write of bufB

  hipMemsetAsync(bcnt, 0, (size_t)NB_MAX*4, stream);

  int nb   = (n + RB-1) >> RB_SHIFT;          // buckets actually used
  int ncb  = (e + CHUNK-1) / CHUNK;           // binning blocks
  k_bhist     <<<ncb, 256, 0, stream>>>(dstp, bcnt, e);
  k_bscan     <<<1,   256, 0, stream>>>(bcnt, bbase, bcur, e);
  k_binscatter<<<ncb, 256, 0, stream>>>(srcp, dstp, bcur, binned, e);
  k_localcsr  <<<nb,  256, 0, stream>>>(binned, bbase, rp, csr, dinv, n, e);

  dim3 gg((n+63)/64, 2);
  k_gemm128<<<gg,          256, 0, stream>>>(x,    W0, dinv, bufA, n);
  k_agg128 <<<(n+7)/8,     256, 0, stream>>>(bufA, rp, csr, dinv, b0, bufB, n, 1);
  k_gemm128<<<gg,          256, 0, stream>>>(bufB, W1, dinv, bufA, n);
  k_agg128 <<<(n+7)/8,     256, 0, stream>>>(bufA, rp, csr, dinv, b1, bufB, n, 1);
  k_gemm5  <<<(n+31)/32,   256, 0, stream>>>(bufB, W2, dinv, bufA, n);
  k_agg5   <<<((n*8)+255)/256,256,0,stream>>>(bufA, rp, csr, dinv, b2, (float*)d_out, n);
}

// Round 6
// 443.897 us; speedup vs baseline: 1.4304x; 1.0907x over previous
//
#include <hip/hip_runtime.h>

#define DF 128
#define RB 512            // nodes per bucket (power of two)
#define RB_SHIFT 9
#define NB_MAX 256        // supports n <= 131072
#define CHUNK 8192        // edges per binning block

// ---------------- CSR build (bucketed, coalesced) ----------------

__global__ void k_bhist(const int* __restrict__ dst, int* __restrict__ bcnt, int e){
  __shared__ int h[NB_MAX];
  int t = threadIdx.x;
  h[t] = 0;
  __syncthreads();
  int base = blockIdx.x*CHUNK;
  for(int k=0;k<CHUNK/256;k++){
    int i = base + t + k*256;
    if(i<e) atomicAdd(&h[dst[i]>>RB_SHIFT], 1);
  }
  __syncthreads();
  if(h[t]) atomicAdd(&bcnt[t], h[t]);
}

__global__ void k_bscan(const int* __restrict__ bcnt, int* __restrict__ bbase,
                        int* __restrict__ bcur, int e){
  __shared__ int sh[NB_MAX];
  int t = threadIdx.x;
  int c = bcnt[t];
  sh[t] = c;
  __syncthreads();
  for(int off=1; off<256; off<<=1){
    int v = (t>=off)? sh[t-off]:0;
    __syncthreads();
    sh[t]+=v;
    __syncthreads();
  }
  int excl = sh[t]-c;
  bbase[t]=excl; bcur[t]=excl;
  if(t==255) bbase[256]=sh[255];   // == e
}

__launch_bounds__(256)
__global__ void k_binscatter(const int* __restrict__ src, const int* __restrict__ dst,
                             int* __restrict__ bcur, int2* __restrict__ binned, int e){
  __shared__ int h[NB_MAX];
  __shared__ int lexcl[NB_MAX];
  __shared__ int lcur[NB_MAX];
  __shared__ int gbase[NB_MAX];
  __shared__ int2 pairs[CHUNK];
  int t = threadIdx.x;
  int c0 = blockIdx.x*CHUNK;
  int cc = min(CHUNK, e - c0);
  h[t]=0;
  __syncthreads();
  for(int k=0;k<CHUNK/256;k++){
    int i = t + k*256;
    if(i<cc) atomicAdd(&h[dst[c0+i]>>RB_SHIFT], 1);
  }
  __syncthreads();
  int hc = h[t];
  lexcl[t]=hc;
  __syncthreads();
  for(int off=1; off<256; off<<=1){
    int v = (t>=off)? lexcl[t-off]:0;
    __syncthreads();
    lexcl[t]+=v;
    __syncthreads();
  }
  int incl = lexcl[t];
  lexcl[t] = incl - hc;
  lcur[t]  = incl - hc;
  gbase[t] = hc ? atomicAdd(&bcur[t], hc) : 0;
  __syncthreads();
  for(int k=0;k<CHUNK/256;k++){
    int i = t + k*256;
    if(i<cc){
      int d = dst[c0+i], s = src[c0+i];
      int lp = atomicAdd(&lcur[d>>RB_SHIFT], 1);
      pairs[lp] = make_int2(d, s);
    }
  }
  __syncthreads();
  for(int k=0;k<CHUNK/256;k++){
    int p = t + k*256;
    if(p<cc){
      int2 pr = pairs[p];
      int b = pr.x>>RB_SHIFT;
      binned[gbase[b] + (p - lexcl[b])] = pr;
    }
  }
}

__launch_bounds__(256)
__global__ void k_localcsr(const int2* __restrict__ binned, const int* __restrict__ bbase,
                           int* __restrict__ rp, int* __restrict__ csr,
                           float* __restrict__ dinv, int n, int e){
  __shared__ int cnt[RB];
  __shared__ int sh[256];
  __shared__ int cur[RB];
  int b = blockIdx.x, t = threadIdx.x;
  int node0 = b<<RB_SHIFT;
  int e0 = bbase[b], e1 = bbase[b+1];
  cnt[t]=0; cnt[t+256]=0;
  __syncthreads();
  for(int i=e0+t; i<e1; i+=256)
    atomicAdd(&cnt[binned[i].x - node0], 1);
  __syncthreads();
  int c0 = cnt[2*t], c1 = cnt[2*t+1];
  int s = c0+c1;
  sh[t]=s;
  __syncthreads();
  for(int off=1; off<256; off<<=1){
    int v = (t>=off)? sh[t-off]:0;
    __syncthreads();
    sh[t]+=v;
    __syncthreads();
  }
  int excl = sh[t]-s;
  int g0 = node0+2*t, g1 = node0+2*t+1;
  if(g0<n){ rp[g0]=e0+excl;    dinv[g0]=rsqrtf((float)(c0+1)); }
  if(g1<n){ rp[g1]=e0+excl+c0; dinv[g1]=rsqrtf((float)(c1+1)); }
  cur[2*t]=excl; cur[2*t+1]=excl+c0;
  if(b==0 && t==0) rp[n]=e;
  __syncthreads();
  for(int i=e0+t; i<e1; i+=256){
    int2 pr = binned[i];
    int lp = atomicAdd(&cur[pr.x - node0], 1);
    csr[e0+lp] = pr.y;
  }
}

// ---------------- prescale: g0 = dinv .* x ----------------

__global__ void k_prescale(const float* __restrict__ x, const float* __restrict__ dinv,
                           float* __restrict__ g, int n){
  int i = blockIdx.x*256 + threadIdx.x;     // float4 index
  if(i < n*(DF/4)){
    float4 v = ((const float4*)x)[i];
    float dv = dinv[i>>5];
    v.x*=dv; v.y*=dv; v.z*=dv; v.w*=dv;
    ((float4*)g)[i] = v;
  }
}

// ---------------- Fused layer: gather(g) -> z=dv*s -> y=zW+b -> act ----------------
// g rows are pre-scaled (dinv_j * h_j). 32 nodes/block, 256 threads.
// Phase 1: 8 groups of 32 lanes each gather 4 nodes into LDS z.
// Phase 2: each thread computes 4 nodes x 4 features over full K=128.
// scale_out=1: out = dinv*relu(y)   (feeds next fused layer's gather)
// scale_out=0: out = relu(y)        (plain h, feeds gemm5)

__launch_bounds__(256, 6)
__global__ void k_fused(const float* __restrict__ g, const int* __restrict__ rp,
                        const int* __restrict__ cs, const float* __restrict__ dinv,
                        const float* __restrict__ W, const float* __restrict__ bias,
                        float* __restrict__ out, int n, int scale_out){
  __shared__ float zs[32][132];
  int t = threadIdx.x;
  int grp = t>>5, lane = t&31;
  int node0 = blockIdx.x*32;
  int c4 = lane*4;
  // ---- phase 1: gather ----
  for(int nn=0; nn<4; nn++){
    int node = node0 + grp*4 + nn;
    if(node<n){
      float4 acc = *(const float4*)(g + (size_t)node*DF + c4);   // self (pre-scaled)
      float4 acc2 = make_float4(0.f,0.f,0.f,0.f);
      int e0=rp[node], e1=rp[node+1];
      int e=e0;
      for(; e+1<e1; e+=2){
        int s0=cs[e], s1=cs[e+1];
        float4 v0 = *(const float4*)(g + (size_t)s0*DF + c4);
        float4 v1 = *(const float4*)(g + (size_t)s1*DF + c4);
        acc.x+=v0.x;  acc.y+=v0.y;  acc.z+=v0.z;  acc.w+=v0.w;
        acc2.x+=v1.x; acc2.y+=v1.y; acc2.z+=v1.z; acc2.w+=v1.w;
      }
      if(e<e1){
        int s0=cs[e];
        float4 v0=*(const float4*)(g + (size_t)s0*DF + c4);
        acc.x+=v0.x; acc.y+=v0.y; acc.z+=v0.z; acc.w+=v0.w;
      }
      float dv = dinv[node];
      acc.x = dv*(acc.x+acc2.x);
      acc.y = dv*(acc.y+acc2.y);
      acc.z = dv*(acc.z+acc2.z);
      acc.w = dv*(acc.w+acc2.w);
      *(float4*)&zs[grp*4+nn][c4] = acc;
    }
  }
  __syncthreads();
  // ---- phase 2: y = z @ W + b ----
  const float4* Wr = (const float4*)W;      // [128][32] float4 view
  int r0 = grp*4;
  float4 a0 = make_float4(0.f,0.f,0.f,0.f);
  float4 a1 = a0, a2 = a0, a3 = a0;
  for(int k=0;k<128;k+=4){
    float4 s0 = *(const float4*)&zs[r0  ][k];
    float4 s1 = *(const float4*)&zs[r0+1][k];
    float4 s2 = *(const float4*)&zs[r0+2][k];
    float4 s3 = *(const float4*)&zs[r0+3][k];
#define STEP(KK, C) { float4 w = Wr[(k+KK)*32 + lane];                     \
    a0.x = fmaf(s0.C, w.x, a0.x); a0.y = fmaf(s0.C, w.y, a0.y);            \
    a0.z = fmaf(s0.C, w.z, a0.z); a0.w = fmaf(s0.C, w.w, a0.w);            \
    a1.x = fmaf(s1.C, w.x, a1.x); a1.y = fmaf(s1.C, w.y, a1.y);            \
    a1.z = fmaf(s1.C, w.z, a1.z); a1.w = fmaf(s1.C, w.w, a1.w);            \
    a2.x = fmaf(s2.C, w.x, a2.x); a2.y = fmaf(s2.C, w.y, a2.y);            \
    a2.z = fmaf(s2.C, w.z, a2.z); a2.w = fmaf(s2.C, w.w, a2.w);            \
    a3.x = fmaf(s3.C, w.x, a3.x); a3.y = fmaf(s3.C, w.y, a3.y);            \
    a3.z = fmaf(s3.C, w.z, a3.z); a3.w = fmaf(s3.C, w.w, a3.w); }
    STEP(0, x) STEP(1, y) STEP(2, z) STEP(3, w)
#undef STEP
  }
  float4 bz = ((const float4*)bias)[lane];
  float4 av[4] = {a0, a1, a2, a3};
  for(int nn=0; nn<4; nn++){
    int node = node0 + r0 + nn;
    if(node<n){
      float4 y = av[nn];
      y.x += bz.x; y.y += bz.y; y.z += bz.z; y.w += bz.w;
      y.x = fmaxf(y.x, 0.f); y.y = fmaxf(y.y, 0.f);
      y.z = fmaxf(y.z, 0.f); y.w = fmaxf(y.w, 0.f);
      if(scale_out){
        float dv = dinv[node];
        y.x*=dv; y.y*=dv; y.z*=dv; y.w*=dv;
      }
      *(float4*)(out + (size_t)node*DF + c4) = y;
    }
  }
}

// ---------------- Final layer: 128 -> 5 ----------------

__launch_bounds__(256)
__global__ void k_gemm5(const float* __restrict__ X, const float* __restrict__ W2,
                        const float* __restrict__ dinv, float* __restrict__ out, int n){
  __shared__ float xs[32][129];
  __shared__ float wsh[640];
  int t=threadIdx.x;
  int row0=blockIdx.x*32;
  for(int idx=t; idx<640; idx+=256) wsh[idx]=W2[idx];
  for(int idx=t; idx<1024; idx+=256){
    int r=idx>>5, k4=(idx&31)*4;
    int gr=row0+r;
    float4 v = (gr<n)? *(const float4*)(X+(size_t)gr*DF+k4) : make_float4(0.f,0.f,0.f,0.f);
    xs[r][k4]=v.x; xs[r][k4+1]=v.y; xs[r][k4+2]=v.z; xs[r][k4+3]=v.w;
  }
  __syncthreads();
  int r=t>>3, c=t&7;
  int gr=row0+r;
  if(c<5 && gr<n){
    float acc=0.f;
    #pragma unroll
    for(int k=0;k<128;k++) acc = fmaf(xs[r][k], wsh[k*5+c], acc);
    out[(size_t)gr*5+c] = dinv[gr]*acc;
  }
}

__global__ void k_agg5(const float* __restrict__ ht, const int* __restrict__ rp,
                       const int* __restrict__ cs, const float* __restrict__ dinv,
                       const float* __restrict__ b2, float* __restrict__ out, int n){
  int idx = blockIdx.x*256+threadIdx.x;
  int node = idx>>3, c = idx&7;
  if(node>=n || c>=5) return;
  float acc = ht[(size_t)node*5+c];
  int e0=rp[node], e1=rp[node+1];
  for(int e=e0;e<e1;e++){
    acc += ht[(size_t)cs[e]*5+c];
  }
  out[(size_t)node*5+c] = fmaf(dinv[node], acc, b2[c]);
}

// ---------------- launch ----------------

extern "C" void kernel_launch(void* const* d_in, const int* in_sizes, int n_in,
                              void* d_out, int out_size, void* d_ws, size_t ws_size,
                              hipStream_t stream){
  const float* x  = (const float*)d_in[0];
  const int*   ei = (const int*)  d_in[1];
  const float* W0 = (const float*)d_in[2];
  const float* b0 = (const float*)d_in[3];
  const float* W1 = (const float*)d_in[4];
  const float* b1 = (const float*)d_in[5];
  const float* W2 = (const float*)d_in[6];
  const float* b2 = (const float*)d_in[7];
  int n = in_sizes[0]/DF;
  int e = in_sizes[1]/2;
  const int* srcp = ei;
  const int* dstp = ei + e;

  char* ws = (char*)d_ws;
  size_t off=0;
  auto take=[&](size_t bytes)->char*{
    char* p = ws+off;
    off = (off+bytes+511)&~(size_t)511;
    return p;
  };
  int*   bcnt = (int*)  take((size_t)NB_MAX*4);
  int*   bbase= (int*)  take((size_t)(NB_MAX+1)*4);
  int*   bcur = (int*)  take((size_t)NB_MAX*4);
  int*   rp   = (int*)  take((size_t)(n+1)*4);
  int*   csr  = (int*)  take((size_t)e*4);
  float* dinv = (float*)take((size_t)n*4);
  float* bufA = (float*)take((size_t)n*DF*4);
  float* bufB = (float*)take((size_t)n*DF*4);
  int2*  binned = (int2*)bufB;   // dead before first write of bufB

  hipMemsetAsync(bcnt, 0, (size_t)NB_MAX*4, stream);

  int nb   = (n + RB-1) >> RB_SHIFT;
  int ncb  = (e + CHUNK-1) / CHUNK;
  k_bhist     <<<ncb, 256, 0, stream>>>(dstp, bcnt, e);
  k_bscan     <<<1,   256, 0, stream>>>(bcnt, bbase, bcur, e);
  k_binscatter<<<ncb, 256, 0, stream>>>(srcp, dstp, bcur, binned, e);
  k_localcsr  <<<nb,  256, 0, stream>>>(binned, bbase, rp, csr, dinv, n, e);

  int nfb = (n+31)/32;
  k_prescale<<<(n*(DF/4)+255)/256, 256, 0, stream>>>(x, dinv, bufA, n);
  // layer 1: gather g0(bufA) -> bufB = dinv*relu(y)
  k_fused   <<<nfb, 256, 0, stream>>>(bufA, rp, csr, dinv, W0, b0, bufB, n, 1);
  // layer 2: gather g1(bufB) -> bufA = relu(y)  (plain h2)
  k_fused   <<<nfb, 256, 0, stream>>>(bufB, rp, csr, dinv, W1, b1, bufA, n, 0);
  // layer 3: ht = dinv*(h2 @ W2) in bufB, then aggregate
  k_gemm5   <<<(n+31)/32, 256, 0, stream>>>(bufA, W2, dinv, (float*)bufB, n);
  k_agg5    <<<((n*8)+255)/256, 256, 0, stream>>>((float*)bufB, rp, csr, dinv, b2, (float*)d_out, n);
}